// Round 8
// baseline (198.331 us; speedup 1.0000x reference)
//
#include <hip/hip_runtime.h>
#include <hip/hip_bf16.h>

// Problem constants (fixed by setup_inputs)
#define B_SZ 8
#define H_SZ 32     // image rows
#define W_SZ 64     // image cols
#define N_SZ 2048   // H*W
#define C_SZ 512
#define NH 8        // heads
#define HD 64       // head dim
// window 7x11 -> +-3 rows, +-5 cols

using u16 = unsigned short;
typedef __attribute__((ext_vector_type(8))) short s16x8;
typedef __attribute__((ext_vector_type(4))) float f32x4;

__device__ __forceinline__ float bf2f(u16 u) {
    union { unsigned int i; float f; } c; c.i = ((unsigned int)u) << 16; return c.f;
}
__device__ __forceinline__ u16 f2bf(float f) {
    union { float f; unsigned int i; } c; c.f = f;
    unsigned int r = c.i + 0x7fffu + ((c.i >> 16) & 1u);  // RNE
    return (u16)(r >> 16);
}
__device__ __forceinline__ ushort4 pack4(f32x4 a) {
    ushort4 s = { f2bf(a[0]), f2bf(a[1]), f2bf(a[2]), f2bf(a[3]) };
    return s;
}

// async global->LDS, 16B per lane; LDS dest must be wave-uniform base + lane*16
#define GLL16(gp, lp) __builtin_amdgcn_global_load_lds( \
    (const __attribute__((address_space(1))) unsigned int*)(gp), \
    (__attribute__((address_space(3))) unsigned int*)(lp), 16, 0, 0)

// 64-elem-row swizzle (attn): chunk c of row r at slot c^(r&7)
__device__ __forceinline__ int lds_off(int row, int chunk) {
    return (row * 8 + (chunk ^ (row & 7))) * 8;
}
// 32-elem-row swizzle (GEMMs, BK=32): 4 chunks/row, slot = c ^ ((r>>1)&3).
// Read banks: 16 lanes -> 8 distinct 4-bank groups x2 lanes = 2-way = free.
__device__ __forceinline__ int lds_off32(int row, int chunk) {
    return row * 32 + (chunk ^ ((row >> 1) & 3)) * 8;
}

// ---------------- fused fp32 -> bf16 convert (x, qkv_w [q-rows scaled], proj_w) ----
#define NX4 2097152   // x float4 count (16384*512/4)
#define NQ4 196608    // qkv_w float4 count
#define NP4 65536     // proj_w float4 count
__global__ __launch_bounds__(256)
void conv_all(const float* __restrict__ x, const float* __restrict__ qw,
              const float* __restrict__ pw, u16* __restrict__ xb,
              u16* __restrict__ qwb, u16* __restrict__ pwb)
{
    const int i = blockIdx.x * 256 + threadIdx.x;
    const float* src; u16* dst; int idx; float sc = 1.0f;
    if (i < NX4)             { src = x;  dst = xb;  idx = i; }
    else if (i < NX4 + NQ4)  { src = qw; dst = qwb; idx = i - NX4;
                               if (idx < 65536) sc = 0.125f; }  // q-rows: fold 64^-0.5
    else                     { src = pw; dst = pwb; idx = i - NX4 - NQ4; }
    const float4 v = ((const float4*)src)[idx];
    ushort4 o = { f2bf(v.x * sc), f2bf(v.y * sc), f2bf(v.z * sc), f2bf(v.w * sc) };
    ((ushort4*)dst)[idx] = o;
}

// ---------------- QKV GEMM: 256x256 tiles, BK=32, dbuf LDS, 512 threads -----------
// 8 waves as (wm2 in 0..1)x(wn2 in 0..3), wave tile 128m x 64n.  SWAPPED ordering
// everywhere: acc[j][i] = D[weight][token] (regs d-consecutive).
// n0<512: q (ushort4 [bh][n][d]); <1024: k (same); else v (scalar [bh][d][n]).
// Double-buffered staging: ONE barrier per k-iter; GLL(it+1) flies during MFMA(it).
__global__ __launch_bounds__(512, 2)
void gemm_qkv(const u16* __restrict__ A, const u16* __restrict__ Bw,
              u16* __restrict__ q_ws, u16* __restrict__ k_ws, u16* __restrict__ v_ws)
{
    __shared__ u16 As[2][256 * 32];   // 16 KB per buf
    __shared__ u16 Bs[2][256 * 32];
    const int t = threadIdx.x;
    const int m0 = blockIdx.x * 256;
    const int n0 = blockIdx.y * 256;
    const int wave = t >> 6, lane = t & 63, l16 = lane & 15, quad = lane >> 4;
    const int wm2 = wave >> 2, wn2 = wave & 3;
    const int srow = t >> 2;                       // 0..127
    const int sch  = (t & 3) ^ ((srow >> 1) & 3);  // swizzled k-chunk to fetch

    f32x4 acc[4][8] = {};

    // prologue: stage k-slice 0 into buf 0
    GLL16(A  + (size_t)(m0 +       srow) * C_SZ + sch * 8, &As[0][t * 8]);
    GLL16(A  + (size_t)(m0 + 128 + srow) * C_SZ + sch * 8, &As[0][4096 + t * 8]);
    GLL16(Bw + (size_t)(n0 +       srow) * C_SZ + sch * 8, &Bs[0][t * 8]);
    GLL16(Bw + (size_t)(n0 + 128 + srow) * C_SZ + sch * 8, &Bs[0][4096 + t * 8]);

    for (int it = 0; it < 16; ++it) {
        __syncthreads();                 // drains GLL(it) (in flight during it-1)
        if (it < 15) {
            const int kn = (it + 1) * 32;
            u16* an = As[(it + 1) & 1]; u16* bn = Bs[(it + 1) & 1];
            GLL16(A  + (size_t)(m0 +       srow) * C_SZ + kn + sch * 8, an + t * 8);
            GLL16(A  + (size_t)(m0 + 128 + srow) * C_SZ + kn + sch * 8, an + 4096 + t * 8);
            GLL16(Bw + (size_t)(n0 +       srow) * C_SZ + kn + sch * 8, bn + t * 8);
            GLL16(Bw + (size_t)(n0 + 128 + srow) * C_SZ + kn + sch * 8, bn + 4096 + t * 8);
        }
        const u16* ac = As[it & 1];
        const u16* bc = Bs[it & 1];
        s16x8 fw[4], fx[8];
        #pragma unroll
        for (int j = 0; j < 4; ++j)
            fw[j] = *(const s16x8*)&bc[lds_off32(wn2 * 64 + 16 * j + l16, quad)];
        #pragma unroll
        for (int i = 0; i < 8; ++i)
            fx[i] = *(const s16x8*)&ac[lds_off32(wm2 * 128 + 16 * i + l16, quad)];
        #pragma unroll
        for (int j = 0; j < 4; ++j)
            #pragma unroll
            for (int i = 0; i < 8; ++i)
                acc[j][i] = __builtin_amdgcn_mfma_f32_16x16x32_bf16(fw[j], fx[i], acc[j][i], 0, 0, 0);
    }

    const int bb  = m0 >> 11;                 // batch (block-uniform)
    const int nn0 = (m0 & 2047) + wm2 * 128;
    if (n0 < 1024) {
        // q or k: [bh][n][d], regs d-consecutive -> ushort4
        u16* T = (n0 < 512) ? q_ws : k_ws;
        const int h = ((n0 + wn2 * 64) >> 6) & 7;          // wave-uniform head
        u16* tb = T + ((size_t)bb * NH + h) * (N_SZ * HD);
        #pragma unroll
        for (int j = 0; j < 4; ++j) {
            const int dd = 16 * j + (quad << 2);
            #pragma unroll
            for (int i = 0; i < 8; ++i) {
                const int nn = nn0 + 16 * i + l16;
                *(ushort4*)(tb + (size_t)nn * HD + dd) = pack4(acc[j][i]);
            }
        }
    } else {
        // v: [bh][d][n] transposed -> scalar stores (store-only divergence)
        const int h = ((n0 - 1024 + wn2 * 64) >> 6) & 7;   // wave-uniform head
        u16* vb = v_ws + ((size_t)bb * NH + h) * (HD * N_SZ);
        #pragma unroll
        for (int j = 0; j < 4; ++j)
            #pragma unroll
            for (int r = 0; r < 4; ++r) {
                const int dd = 16 * j + (quad << 2) + r;
                u16* row = vb + (size_t)dd * N_SZ + nn0;
                #pragma unroll
                for (int i = 0; i < 8; ++i)
                    row[16 * i + l16] = f2bf(acc[j][r == 0 ? i : i][r]);   // acc[j][i][r]
            }
    }
}

// ---------------- proj GEMM: 256x128 tiles, BK=32, dbuf LDS, 256 threads ----------
// 4 waves as (wm2 in 0..1)x(wn2 in 0..1), wave tile 128m x 64n, swapped ordering,
// float4 stores + bias.
__global__ __launch_bounds__(256, 2)
void gemm_proj(const u16* __restrict__ A, const u16* __restrict__ Bw,
               const float* __restrict__ bias, float* __restrict__ outp)
{
    __shared__ u16 As[2][256 * 32];
    __shared__ u16 Bs[2][128 * 32];
    const int t = threadIdx.x;
    const int m0 = blockIdx.x * 256;
    const int n0 = blockIdx.y * 128;
    const int wave = t >> 6, lane = t & 63, l16 = lane & 15, quad = lane >> 4;
    const int wm2 = wave >> 1, wn2 = wave & 1;
    const int srow = t >> 2;                       // 0..63
    const int sch  = (t & 3) ^ ((srow >> 1) & 3);

    f32x4 acc[4][8] = {};

    #pragma unroll
    for (int g = 0; g < 4; ++g)
        GLL16(A + (size_t)(m0 + 64 * g + srow) * C_SZ + sch * 8, &As[0][g * 2048 + t * 8]);
    #pragma unroll
    for (int g = 0; g < 2; ++g)
        GLL16(Bw + (size_t)(n0 + 64 * g + srow) * C_SZ + sch * 8, &Bs[0][g * 2048 + t * 8]);

    for (int it = 0; it < 16; ++it) {
        __syncthreads();
        if (it < 15) {
            const int kn = (it + 1) * 32;
            u16* an = As[(it + 1) & 1]; u16* bn = Bs[(it + 1) & 1];
            #pragma unroll
            for (int g = 0; g < 4; ++g)
                GLL16(A + (size_t)(m0 + 64 * g + srow) * C_SZ + kn + sch * 8, an + g * 2048 + t * 8);
            #pragma unroll
            for (int g = 0; g < 2; ++g)
                GLL16(Bw + (size_t)(n0 + 64 * g + srow) * C_SZ + kn + sch * 8, bn + g * 2048 + t * 8);
        }
        const u16* ac = As[it & 1];
        const u16* bc = Bs[it & 1];
        s16x8 fw[4], fx[8];
        #pragma unroll
        for (int j = 0; j < 4; ++j)
            fw[j] = *(const s16x8*)&bc[lds_off32(wn2 * 64 + 16 * j + l16, quad)];
        #pragma unroll
        for (int i = 0; i < 8; ++i)
            fx[i] = *(const s16x8*)&ac[lds_off32(wm2 * 128 + 16 * i + l16, quad)];
        #pragma unroll
        for (int j = 0; j < 4; ++j)
            #pragma unroll
            for (int i = 0; i < 8; ++i)
                acc[j][i] = __builtin_amdgcn_mfma_f32_16x16x32_bf16(fw[j], fx[i], acc[j][i], 0, 0, 0);
    }

    #pragma unroll
    for (int j = 0; j < 4; ++j) {
        const int cb = n0 + wn2 * 64 + 16 * j + (quad << 2);
        const float4 bv = *(const float4*)&bias[cb];
        #pragma unroll
        for (int i = 0; i < 8; ++i) {
            const int gm = m0 + wm2 * 128 + 16 * i + l16;
            float4 st = { acc[j][i][0] + bv.x, acc[j][i][1] + bv.y,
                          acc[j][i][2] + bv.z, acc[j][i][3] + bv.w };
            *(float4*)&outp[(size_t)gm * C_SZ + cb] = st;
        }
    }
}

// ---------------- MFMA local attention: 2 image rows / block (round-7) -----------
__global__ __launch_bounds__(256)
void attn_mfma(const u16* __restrict__ q_ws, const u16* __restrict__ k_ws,
               const u16* __restrict__ vt_ws, u16* __restrict__ o_ws)
{
    __shared__ u16 KV[2][64 * 64];   // [0]=K row, [1]=Vt row; Q staging at start
    __shared__ u16 Ps[4][16 * 40];   // per-wave P, [q16][key32], stride 40 elems

    const int t = threadIdx.x, wave = t >> 6, lane = t & 63;
    const int l16 = lane & 15, quad = lane >> 4;
    const int u  = blockIdx.x;
    const int p  = u & 15;           // row pair
    const int bh = u >> 4;
    const int r0 = 2 * p, r1 = 2 * p + 1;
    const size_t base = (size_t)bh * (N_SZ * HD);
    const int srow = t >> 3;
    const int sch  = (t & 7) ^ (srow & 7);

    const u16* qg = q_ws + base + (size_t)r0 * (64 * HD);
    u16* Qst = &KV[0][0];
    #pragma unroll
    for (int g = 0; g < 4; ++g)
        GLL16(qg + (size_t)(srow + 32 * g) * 64 + sch * 8, Qst + g * 2048 + t * 8);
    __syncthreads();

    s16x8 aQ[2][2];
    #pragma unroll
    for (int s = 0; s < 2; ++s) {
        const int Rq = 64 * s + 16 * wave + l16;
        aQ[s][0] = *(const s16x8*)&Qst[lds_off(Rq, quad)];
        aQ[s][1] = *(const s16x8*)&Qst[lds_off(Rq, 4 + quad)];
    }

    const int kb = min(max(16 * wave - 8, 0), 32);   // 0, 8, 24, 32

    f32x4 accO[2][4] = {};
    float lp[2][4] = {};

    const int hlo = (r0 - 3 < 0) ? 0 : r0 - 3;
    const int hhi = (r1 + 3 > H_SZ - 1) ? H_SZ - 1 : r1 + 3;

    for (int hh = hlo; hh <= hhi; ++hh) {
        __syncthreads();
        const u16* kg = k_ws + base + (size_t)hh * (64 * HD);
        GLL16(kg + (size_t)srow        * 64 + sch * 8, &KV[0][t * 8]);
        GLL16(kg + (size_t)(srow + 32) * 64 + sch * 8, &KV[0][2048 + t * 8]);
        const u16* vg = vt_ws + base + (size_t)hh * 64;
        GLL16(vg + (size_t)srow        * N_SZ + sch * 8, &KV[1][t * 8]);
        GLL16(vg + (size_t)(srow + 32) * N_SZ + sch * 8, &KV[1][2048 + t * 8]);
        __syncthreads();

        s16x8 bK[2][2];
        #pragma unroll
        for (int j = 0; j < 2; ++j) {
            const int Rk = kb + 16 * j + l16;
            bK[j][0] = *(const s16x8*)&KV[0][lds_off(Rk, quad)];
            bK[j][1] = *(const s16x8*)&KV[0][lds_off(Rk, 4 + quad)];
        }
        s16x8 vf[4];
        #pragma unroll
        for (int j = 0; j < 4; ++j)
            vf[j] = *(const s16x8*)&KV[1][lds_off(16 * j + l16, (kb >> 3) + quad)];

        #pragma unroll
        for (int s = 0; s < 2; ++s) {
            const int dh = hh - (r0 + s);
            if (dh * dh > 9) continue;     // wave-uniform: row out of +-3 range
            f32x4 z[2] = {{0.f,0.f,0.f,0.f},{0.f,0.f,0.f,0.f}};
            #pragma unroll
            for (int j = 0; j < 2; ++j) {
                z[j] = __builtin_amdgcn_mfma_f32_16x16x32_bf16(aQ[s][0], bK[j][0], z[j], 0, 0, 0);
                z[j] = __builtin_amdgcn_mfma_f32_16x16x32_bf16(aQ[s][1], bK[j][1], z[j], 0, 0, 0);
            }
            #pragma unroll
            for (int j = 0; j < 2; ++j) {
                const int ww = kb + 16 * j + l16;
                #pragma unroll
                for (int r = 0; r < 4; ++r) {
                    const int dw = ww - (16 * wave + quad * 4 + r);
                    const float pv = (dw * dw <= 25) ? __expf(z[j][r]) : 0.f;
                    const u16 pb = f2bf(pv);
                    lp[s][r] += bf2f(pb);
                    Ps[wave][(quad * 4 + r) * 40 + 16 * j + l16] = pb;
                }
            }
            s16x8 aP = *(const s16x8*)&Ps[wave][l16 * 40 + quad * 8];
            #pragma unroll
            for (int j = 0; j < 4; ++j)
                accO[s][j] = __builtin_amdgcn_mfma_f32_16x16x32_bf16(vf[j], aP, accO[s][j], 0, 0, 0);
        }
    }

    #pragma unroll
    for (int s = 0; s < 2; ++s)
        #pragma unroll
        for (int r = 0; r < 4; ++r) {
            lp[s][r] += __shfl_xor(lp[s][r], 1);
            lp[s][r] += __shfl_xor(lp[s][r], 2);
            lp[s][r] += __shfl_xor(lp[s][r], 4);
            lp[s][r] += __shfl_xor(lp[s][r], 8);
        }

    const int srcl = (l16 >> 2) << 4;
    const int rr   = l16 & 3;
    float inv[2];
    #pragma unroll
    for (int s = 0; s < 2; ++s) {
        const float a0 = __shfl(lp[s][0], srcl);
        const float a1 = __shfl(lp[s][1], srcl);
        const float a2 = __shfl(lp[s][2], srcl);
        const float a3 = __shfl(lp[s][3], srcl);
        const float lq = (rr == 0) ? a0 : (rr == 1) ? a1 : (rr == 2) ? a2 : a3;
        inv[s] = 1.0f / lq;
    }

    const int bb = bh >> 3, h = bh & 7;
    #pragma unroll
    for (int s = 0; s < 2; ++s) {
        const int row = (r0 + s) * 64 + 16 * wave + l16;
        u16* ob = o_ws + ((size_t)bb * N_SZ + row) * C_SZ + h * 64 + (quad << 2);
        #pragma unroll
        for (int j = 0; j < 4; ++j) {
            ushort4 st = { f2bf(accO[s][j][0] * inv[s]), f2bf(accO[s][j][1] * inv[s]),
                           f2bf(accO[s][j][2] * inv[s]), f2bf(accO[s][j][3] * inv[s]) };
            *(ushort4*)(ob + 16 * j) = st;
        }
    }
}

extern "C" void kernel_launch(void* const* d_in, const int* in_sizes, int n_in,
                              void* d_out, int out_size, void* d_ws, size_t ws_size,
                              hipStream_t stream)
{
    const float* x      = (const float*)d_in[0];
    const float* qkv_w  = (const float*)d_in[1];
    const float* proj_w = (const float*)d_in[2];
    const float* proj_b = (const float*)d_in[3];
    float* outp = (float*)d_out;

    const size_t seg = (size_t)B_SZ * NH * N_SZ * HD;  // 8388608 elems
    u16* q_ws = (u16*)d_ws;
    u16* k_ws = q_ws + seg;
    u16* v_ws = k_ws + seg;      // transposed layout [bh][d][n]
    u16* o_ws = v_ws + seg;
    u16* xb   = o_ws + seg;                       // x as bf16 (8.4M elems)
    u16* qwb  = xb + (size_t)16384 * 512;         // qkv_w bf16 (786432)
    u16* pwb  = qwb + (size_t)1536 * 512;         // proj_w bf16 (262144)

    conv_all<<<9216, 256, 0, stream>>>(x, qkv_w, proj_w, xb, qwb, pwb);

    // QKV GEMM: M=16384, N=1536, K=512 — 256x256 tiles
    gemm_qkv<<<dim3(64, 6), 512, 0, stream>>>(xb, qwb, q_ws, k_ws, v_ws);
    // local attention, one block per (b,h,row-pair)
    attn_mfma<<<B_SZ * NH * (H_SZ / 2), 256, 0, stream>>>(q_ws, k_ws, v_ws, o_ws);
    // proj GEMM: M=16384, N=512, K=512 — 256x128 tiles (+bias, fp32 out)
    gemm_proj<<<dim3(64, 4), 256, 0, stream>>>(o_ws, pwb, proj_b, outp);
}